// Round 1
// baseline (1607.894 us; speedup 1.0000x reference)
//
#include <hip/hip_runtime.h>
#include <hip/hip_bf16.h>
#include <math.h>

// DenseGCN3Layer on MI355X.
// Pipeline:
//   deg histogram -> dinv -> CSR (scan+fill) ->
//   h1 = x@W1                     [N,64]
//   x1 = relu(agg(h1)+b1)        (gather CSR, wave/node)
//   h2 = x1@W2                    [N,32]
//   pre2 = x@Ws02+bs02            [N,32]
//   x2 = relu(agg(h2)+b2+pre2)
//   h3 = x2@W3                    [N,16]
//   pre3 = x@Ws03+bs03 + x1@Ws13+bs13
//   out = sigmoid( relu(agg(h3)+b3+pre3) @ Wout + bout )   (fused epilogue)

// ---------------------------------------------------------------- CSR build

__global__ __launch_bounds__(256) void count_deg_kernel(
    const int* __restrict__ dst, int E, int* __restrict__ deg)
{
    int e = blockIdx.x * 256 + threadIdx.x;
    if (e < E) atomicAdd(&deg[dst[e]], 1);
}

__global__ __launch_bounds__(256) void dinv_kernel(
    const int* __restrict__ deg, float* __restrict__ dinv, int N)
{
    int i = blockIdx.x * 256 + threadIdx.x;
    if (i < N) dinv[i] = rsqrtf((float)deg[i] + 1.0f);
}

// Single-block exclusive scan over deg -> row_off, cursor. N ~ 1e5.
__global__ __launch_bounds__(1024) void scan_kernel(
    const int* __restrict__ deg, int* __restrict__ row_off,
    int* __restrict__ cursor, int N)
{
    __shared__ int part[1024];
    const int tid = threadIdx.x;
    const int chunk = (N + 1023) / 1024;
    const int start = min(tid * chunk, N);
    const int end   = min(start + chunk, N);
    int s = 0;
    for (int i = start; i < end; ++i) s += deg[i];
    part[tid] = s;
    __syncthreads();
    for (int off = 1; off < 1024; off <<= 1) {
        int v = (tid >= off) ? part[tid - off] : 0;
        __syncthreads();
        part[tid] += v;
        __syncthreads();
    }
    int run = part[tid] - s;   // exclusive prefix of this thread's chunk
    for (int i = start; i < end; ++i) {
        row_off[i] = run;
        cursor[i]  = run;
        run += deg[i];
    }
    if (tid == 1023) row_off[N] = part[1023];
}

__global__ __launch_bounds__(256) void fill_kernel(
    const int* __restrict__ src, const int* __restrict__ dst, int E,
    int* __restrict__ cursor, int* __restrict__ col)
{
    int e = blockIdx.x * 256 + threadIdx.x;
    if (e < E) {
        int d = dst[e];
        int pos = atomicAdd(&cursor[d], 1);
        col[pos] = src[e];
    }
}

// ---------------------------------------------------------------- GEMM (fp32 VALU)
// C[N,F] = X[N,K] @ W[K,F] (+ bias[f]) (+= C if accumulate)
// 16 nodes per block, 256 threads: f = tid%F, node-group = tid/F,
// NPT = F/16 nodes per thread. K tiled by KC<=64 -> LDS <= 20 KB.

template<int K, int F>
__global__ __launch_bounds__(256) void gemm_kernel(
    const float* __restrict__ X, const float* __restrict__ W,
    const float* __restrict__ bias, float* __restrict__ C,
    int N, int accumulate)
{
    constexpr int NB  = 16;
    constexpr int G   = 256 / F;      // node groups per block
    constexpr int NPT = NB / G;       // nodes per thread
    constexpr int KC  = (K < 64) ? K : 64;
    __shared__ __align__(16) float Xs[NB * KC];
    __shared__ __align__(16) float Ws[KC * F];

    const int tid = threadIdx.x;
    const int f   = tid % F;
    const int ng  = tid / F;
    const int n0  = blockIdx.x * NB;

    float acc[NPT];
#pragma unroll
    for (int j = 0; j < NPT; ++j) acc[j] = 0.f;

    for (int kc = 0; kc < K; kc += KC) {
        for (int i = tid; i < NB * KC; i += 256) {
            int r = i / KC, c = i % KC;
            int n = n0 + r;
            Xs[i] = (n < N) ? X[(size_t)n * K + kc + c] : 0.f;
        }
        for (int i = tid; i < KC * F; i += 256) {
            int kk = i / F, ff = i % F;
            Ws[i] = W[(size_t)(kc + kk) * F + ff];
        }
        __syncthreads();
#pragma unroll 4
        for (int k = 0; k < KC; k += 4) {
            float w0 = Ws[(k + 0) * F + f];
            float w1 = Ws[(k + 1) * F + f];
            float w2 = Ws[(k + 2) * F + f];
            float w3 = Ws[(k + 3) * F + f];
#pragma unroll
            for (int j = 0; j < NPT; ++j) {
                const float4 xv =
                    *reinterpret_cast<const float4*>(&Xs[(ng * NPT + j) * KC + k]);
                acc[j] = fmaf(xv.x, w0, acc[j]);
                acc[j] = fmaf(xv.y, w1, acc[j]);
                acc[j] = fmaf(xv.z, w2, acc[j]);
                acc[j] = fmaf(xv.w, w3, acc[j]);
            }
        }
        __syncthreads();
    }

    const float bv = bias ? bias[f] : 0.f;
#pragma unroll
    for (int j = 0; j < NPT; ++j) {
        int n = n0 + ng * NPT + j;
        if (n < N) {
            size_t idx = (size_t)n * F + f;
            float v = acc[j] + bv;
            if (accumulate) v += C[idx];
            C[idx] = v;
        }
    }
}

// ---------------------------------------------------------------- aggregation
// One wave per node. lanes: f = lane&(F-1), eo = lane/F edges in flight.
// out[i,f] = relu( dinv[i]*sum_j dinv[j]*h[j,f] + dinv[i]^2*h[i,f]
//                  + bias[f] + pre[i,f] )
// FINAL: fuse x3@Wout+bout -> sigmoid, one scalar per node.

template<int F, bool FINAL>
__global__ __launch_bounds__(256) void agg_kernel(
    const float* __restrict__ h, const float* __restrict__ dinv,
    const int* __restrict__ row_off, const int* __restrict__ col,
    const float* __restrict__ bias, const float* __restrict__ pre,
    const float* __restrict__ Wout, const float* __restrict__ bout,
    float* __restrict__ out, int N)
{
    const int lane = threadIdx.x & 63;
    const int wv   = threadIdx.x >> 6;
    const int i    = blockIdx.x * 4 + wv;
    if (i >= N) return;

    const int f  = lane & (F - 1);
    const int eo = lane / F;
    constexpr int EPW = 64 / F;

    float acc = 0.f;
    const int s = row_off[i];
    const int e = row_off[i + 1];
    for (int p = s + eo; p < e; p += EPW) {
        const int j = col[p];
        acc += dinv[j] * h[(size_t)j * F + f];
    }
#pragma unroll
    for (int off = F; off < 64; off <<= 1) acc += __shfl_xor(acc, off, 64);

    const float di = dinv[i];
    float v = di * acc + di * di * h[(size_t)i * F + f] + bias[f];
    if (pre) v += pre[(size_t)i * F + f];
    v = fmaxf(v, 0.f);

    if (!FINAL) {
        if (lane < F) out[(size_t)i * F + f] = v;
    } else {
        float t = v * Wout[f];
#pragma unroll
        for (int off = 1; off < F; off <<= 1) t += __shfl_xor(t, off, 64);
        if (lane == 0) out[i] = 1.0f / (1.0f + expf(-(t + bout[0])));
    }
}

// ---------------------------------------------------------------- launch

extern "C" void kernel_launch(void* const* d_in, const int* in_sizes, int n_in,
                              void* d_out, int out_size, void* d_ws, size_t ws_size,
                              hipStream_t stream)
{
    const float* x    = (const float*)d_in[0];
    const int*   edge = (const int*)d_in[1];
    const float* W1   = (const float*)d_in[2];
    const float* b1   = (const float*)d_in[3];
    const float* W2   = (const float*)d_in[4];
    const float* b2   = (const float*)d_in[5];
    const float* W3   = (const float*)d_in[6];
    const float* b3   = (const float*)d_in[7];
    const float* Ws02 = (const float*)d_in[8];
    const float* bs02 = (const float*)d_in[9];
    const float* Ws03 = (const float*)d_in[10];
    const float* bs03 = (const float*)d_in[11];
    const float* Ws13 = (const float*)d_in[12];
    const float* bs13 = (const float*)d_in[13];
    const float* Wout = (const float*)d_in[14];
    const float* bout = (const float*)d_in[15];

    const int N = in_sizes[0] / 256;
    const int E = in_sizes[1] / 2;
    const int* srcv = edge;       // edge_index[0,:]
    const int* dstv = edge + E;   // edge_index[1,:]

    // workspace carve-up (~117 MB)
    char* ws = (char*)d_ws;
    size_t off = 0;
    auto alloc = [&](size_t bytes) -> void* {
        void* p = ws + off;
        off += (bytes + 255) & ~(size_t)255;
        return p;
    };
    int*   col     = (int*)  alloc((size_t)E * 4);
    int*   deg     = (int*)  alloc((size_t)N * 4);
    int*   cursor  = (int*)  alloc((size_t)N * 4);
    int*   row_off = (int*)  alloc((size_t)(N + 1) * 4);
    float* dinv    = (float*)alloc((size_t)N * 4);
    float* h1      = (float*)alloc((size_t)N * 64 * 4);
    float* x1      = (float*)alloc((size_t)N * 64 * 4);
    float* h2      = (float*)alloc((size_t)N * 32 * 4);
    float* pre2    = (float*)alloc((size_t)N * 32 * 4);
    float* x2      = (float*)alloc((size_t)N * 32 * 4);
    float* h3      = (float*)alloc((size_t)N * 16 * 4);
    float* pre3    = (float*)alloc((size_t)N * 16 * 4);

    // --- graph preprocessing
    hipMemsetAsync(deg, 0, (size_t)N * 4, stream);
    count_deg_kernel<<<(E + 255) / 256, 256, 0, stream>>>(dstv, E, deg);
    dinv_kernel<<<(N + 255) / 256, 256, 0, stream>>>(deg, dinv, N);
    scan_kernel<<<1, 1024, 0, stream>>>(deg, row_off, cursor, N);
    fill_kernel<<<(E + 255) / 256, 256, 0, stream>>>(srcv, dstv, E, cursor, col);

    const int gb = (N + 15) / 16;
    const int ab = (N + 3) / 4;

    // --- layer 1
    gemm_kernel<256, 64><<<gb, 256, 0, stream>>>(x, W1, nullptr, h1, N, 0);
    agg_kernel<64, false><<<ab, 256, 0, stream>>>(h1, dinv, row_off, col,
                                                  b1, nullptr, nullptr, nullptr, x1, N);
    // --- layer 2
    gemm_kernel<64, 32><<<gb, 256, 0, stream>>>(x1, W2, nullptr, h2, N, 0);
    gemm_kernel<256, 32><<<gb, 256, 0, stream>>>(x, Ws02, bs02, pre2, N, 0);
    agg_kernel<32, false><<<ab, 256, 0, stream>>>(h2, dinv, row_off, col,
                                                  b2, pre2, nullptr, nullptr, x2, N);
    // --- layer 3 + output head (fused)
    gemm_kernel<32, 16><<<gb, 256, 0, stream>>>(x2, W3, nullptr, h3, N, 0);
    gemm_kernel<256, 16><<<gb, 256, 0, stream>>>(x, Ws03, bs03, pre3, N, 0);
    gemm_kernel<64, 16><<<gb, 256, 0, stream>>>(x1, Ws13, bs13, pre3, N, 1);
    agg_kernel<16, true><<<ab, 256, 0, stream>>>(h3, dinv, row_off, col,
                                                 b3, pre3, Wout, bout, (float*)d_out, N);
}

// Round 2
// 1320.578 us; speedup vs baseline: 1.2176x; 1.2176x over previous
//
#include <hip/hip_runtime.h>
#include <hip/hip_bf16.h>
#include <math.h>

// DenseGCN3Layer on MI355X — round 2.
// Changes vs r1:
//  * GEMM epilogue stores g = dinv[n]*h[n] in BF16 (halves gather bytes).
//  * agg reads only g (no dinv[src] gather): out = relu(dinv[i]*(sum g_j + g_i)+b+pre)
//  * agg edge loop unrolled x4 with batched col loads (latency hiding).

// ---------------------------------------------------------------- CSR build

__global__ __launch_bounds__(256) void count_deg_kernel(
    const int* __restrict__ dst, int E, int* __restrict__ deg)
{
    int e = blockIdx.x * 256 + threadIdx.x;
    if (e < E) atomicAdd(&deg[dst[e]], 1);
}

__global__ __launch_bounds__(256) void dinv_kernel(
    const int* __restrict__ deg, float* __restrict__ dinv, int N)
{
    int i = blockIdx.x * 256 + threadIdx.x;
    if (i < N) dinv[i] = rsqrtf((float)deg[i] + 1.0f);
}

__global__ __launch_bounds__(1024) void scan_kernel(
    const int* __restrict__ deg, int* __restrict__ row_off,
    int* __restrict__ cursor, int N)
{
    __shared__ int part[1024];
    const int tid = threadIdx.x;
    const int chunk = (N + 1023) / 1024;
    const int start = min(tid * chunk, N);
    const int end   = min(start + chunk, N);
    int s = 0;
    for (int i = start; i < end; ++i) s += deg[i];
    part[tid] = s;
    __syncthreads();
    for (int off = 1; off < 1024; off <<= 1) {
        int v = (tid >= off) ? part[tid - off] : 0;
        __syncthreads();
        part[tid] += v;
        __syncthreads();
    }
    int run = part[tid] - s;
    for (int i = start; i < end; ++i) {
        row_off[i] = run;
        cursor[i]  = run;
        run += deg[i];
    }
    if (tid == 1023) row_off[N] = part[1023];
}

__global__ __launch_bounds__(256) void fill_kernel(
    const int* __restrict__ src, const int* __restrict__ dst, int E,
    int* __restrict__ cursor, int* __restrict__ col)
{
    int e = blockIdx.x * 256 + threadIdx.x;
    if (e < E) {
        int d = dst[e];
        int pos = atomicAdd(&cursor[d], 1);
        col[pos] = src[e];
    }
}

// ---------------------------------------------------------------- GEMM (fp32 VALU)
// C[N,F] = X[N,K] @ W[K,F] (+ bias) ; optional accumulate into C (fp32 out)
// OUT_G: store g = bf16(dinv[n] * (X@W)[n,f]) instead (no bias).

template<int K, int F, bool OUT_G>
__global__ __launch_bounds__(256) void gemm_kernel(
    const float* __restrict__ X, const float* __restrict__ W,
    const float* __restrict__ bias, const float* __restrict__ dinv,
    float* __restrict__ C, __hip_bfloat16* __restrict__ G,
    int N, int accumulate)
{
    constexpr int NB  = 16;
    constexpr int G_  = 256 / F;      // node groups per block
    constexpr int NPT = NB / G_;      // nodes per thread
    constexpr int KC  = (K < 64) ? K : 64;
    __shared__ __align__(16) float Xs[NB * KC];
    __shared__ __align__(16) float Ws[KC * F];

    const int tid = threadIdx.x;
    const int f   = tid % F;
    const int ng  = tid / F;
    const int n0  = blockIdx.x * NB;

    float acc[NPT];
#pragma unroll
    for (int j = 0; j < NPT; ++j) acc[j] = 0.f;

    for (int kc = 0; kc < K; kc += KC) {
        for (int i = tid; i < NB * KC; i += 256) {
            int r = i / KC, c = i % KC;
            int n = n0 + r;
            Xs[i] = (n < N) ? X[(size_t)n * K + kc + c] : 0.f;
        }
        for (int i = tid; i < KC * F; i += 256) {
            int kk = i / F, ff = i % F;
            Ws[i] = W[(size_t)(kc + kk) * F + ff];
        }
        __syncthreads();
#pragma unroll 4
        for (int k = 0; k < KC; k += 4) {
            float w0 = Ws[(k + 0) * F + f];
            float w1 = Ws[(k + 1) * F + f];
            float w2 = Ws[(k + 2) * F + f];
            float w3 = Ws[(k + 3) * F + f];
#pragma unroll
            for (int j = 0; j < NPT; ++j) {
                const float4 xv =
                    *reinterpret_cast<const float4*>(&Xs[(ng * NPT + j) * KC + k]);
                acc[j] = fmaf(xv.x, w0, acc[j]);
                acc[j] = fmaf(xv.y, w1, acc[j]);
                acc[j] = fmaf(xv.z, w2, acc[j]);
                acc[j] = fmaf(xv.w, w3, acc[j]);
            }
        }
        __syncthreads();
    }

#pragma unroll
    for (int j = 0; j < NPT; ++j) {
        int n = n0 + ng * NPT + j;
        if (n < N) {
            size_t idx = (size_t)n * F + f;
            if (OUT_G) {
                G[idx] = __float2bfloat16(dinv[n] * acc[j]);
            } else {
                float v = acc[j] + (bias ? bias[f] : 0.f);
                if (accumulate) v += C[idx];
                C[idx] = v;
            }
        }
    }
}

// ---------------------------------------------------------------- aggregation
// One wave per node; f = lane&(F-1), eo = lane/F (EPW edges in flight per lane
// group), edge loop unrolled x4.
// out[i,f] = relu( dinv[i]*(sum_{j in N(i)} g[j,f] + g[i,f]) + bias[f] + pre[i,f] )
// FINAL: fuse @Wout+bout -> sigmoid.

template<int F, bool FINAL>
__global__ __launch_bounds__(256) void agg_kernel(
    const __hip_bfloat16* __restrict__ g, const float* __restrict__ dinv,
    const int* __restrict__ row_off, const int* __restrict__ col,
    const float* __restrict__ bias, const float* __restrict__ pre,
    const float* __restrict__ Wout, const float* __restrict__ bout,
    float* __restrict__ out, int N)
{
    const int lane = threadIdx.x & 63;
    const int wv   = threadIdx.x >> 6;
    const int i    = blockIdx.x * 4 + wv;
    if (i >= N) return;

    const int f  = lane & (F - 1);
    const int eo = lane / F;
    constexpr int EPW = 64 / F;

    float acc = 0.f;
    const int s = row_off[i];
    const int e = row_off[i + 1];
    int p = s + eo;
    // unrolled x4: batch the index loads, then the row loads -> ~8 in flight
    for (; p + 3 * EPW < e; p += 4 * EPW) {
        const int j0 = col[p];
        const int j1 = col[p + EPW];
        const int j2 = col[p + 2 * EPW];
        const int j3 = col[p + 3 * EPW];
        const float v0 = __bfloat162float(g[(size_t)j0 * F + f]);
        const float v1 = __bfloat162float(g[(size_t)j1 * F + f]);
        const float v2 = __bfloat162float(g[(size_t)j2 * F + f]);
        const float v3 = __bfloat162float(g[(size_t)j3 * F + f]);
        acc += (v0 + v1) + (v2 + v3);
    }
    for (; p < e; p += EPW) {
        const int j = col[p];
        acc += __bfloat162float(g[(size_t)j * F + f]);
    }
#pragma unroll
    for (int off = F; off < 64; off <<= 1) acc += __shfl_xor(acc, off, 64);

    const float di = dinv[i];
    float v = di * (acc + __bfloat162float(g[(size_t)i * F + f])) + bias[f];
    if (pre) v += pre[(size_t)i * F + f];
    v = fmaxf(v, 0.f);

    if (!FINAL) {
        if (lane < F) out[(size_t)i * F + f] = v;
    } else {
        float t = v * Wout[f];
#pragma unroll
        for (int off = 1; off < F; off <<= 1) t += __shfl_xor(t, off, 64);
        if (lane == 0) out[i] = 1.0f / (1.0f + expf(-(t + bout[0])));
    }
}

// ---------------------------------------------------------------- launch

extern "C" void kernel_launch(void* const* d_in, const int* in_sizes, int n_in,
                              void* d_out, int out_size, void* d_ws, size_t ws_size,
                              hipStream_t stream)
{
    const float* x    = (const float*)d_in[0];
    const int*   edge = (const int*)d_in[1];
    const float* W1   = (const float*)d_in[2];
    const float* b1   = (const float*)d_in[3];
    const float* W2   = (const float*)d_in[4];
    const float* b2   = (const float*)d_in[5];
    const float* W3   = (const float*)d_in[6];
    const float* b3   = (const float*)d_in[7];
    const float* Ws02 = (const float*)d_in[8];
    const float* bs02 = (const float*)d_in[9];
    const float* Ws03 = (const float*)d_in[10];
    const float* bs03 = (const float*)d_in[11];
    const float* Ws13 = (const float*)d_in[12];
    const float* bs13 = (const float*)d_in[13];
    const float* Wout = (const float*)d_in[14];
    const float* bout = (const float*)d_in[15];

    const int N = in_sizes[0] / 256;
    const int E = in_sizes[1] / 2;
    const int* srcv = edge;
    const int* dstv = edge + E;

    char* ws = (char*)d_ws;
    size_t off = 0;
    auto alloc = [&](size_t bytes) -> void* {
        void* p = ws + off;
        off += (bytes + 255) & ~(size_t)255;
        return p;
    };
    int*   col     = (int*)  alloc((size_t)E * 4);
    int*   deg     = (int*)  alloc((size_t)N * 4);
    int*   cursor  = (int*)  alloc((size_t)N * 4);
    int*   row_off = (int*)  alloc((size_t)(N + 1) * 4);
    float* dinv    = (float*)alloc((size_t)N * 4);
    __hip_bfloat16* g1 = (__hip_bfloat16*)alloc((size_t)N * 64 * 2);
    __hip_bfloat16* g2 = (__hip_bfloat16*)alloc((size_t)N * 32 * 2);
    __hip_bfloat16* g3 = (__hip_bfloat16*)alloc((size_t)N * 16 * 2);
    float* x1      = (float*)alloc((size_t)N * 64 * 4);
    float* pre2    = (float*)alloc((size_t)N * 32 * 4);
    float* x2      = (float*)alloc((size_t)N * 32 * 4);
    float* pre3    = (float*)alloc((size_t)N * 16 * 4);

    // --- graph preprocessing
    hipMemsetAsync(deg, 0, (size_t)N * 4, stream);
    count_deg_kernel<<<(E + 255) / 256, 256, 0, stream>>>(dstv, E, deg);
    dinv_kernel<<<(N + 255) / 256, 256, 0, stream>>>(deg, dinv, N);
    scan_kernel<<<1, 1024, 0, stream>>>(deg, row_off, cursor, N);
    fill_kernel<<<(E + 255) / 256, 256, 0, stream>>>(srcv, dstv, E, cursor, col);

    const int gb = (N + 15) / 16;
    const int ab = (N + 3) / 4;

    // --- layer 1
    gemm_kernel<256, 64, true><<<gb, 256, 0, stream>>>(x, W1, nullptr, dinv,
                                                       nullptr, g1, N, 0);
    agg_kernel<64, false><<<ab, 256, 0, stream>>>(g1, dinv, row_off, col,
                                                  b1, nullptr, nullptr, nullptr, x1, N);
    // --- layer 2
    gemm_kernel<64, 32, true><<<gb, 256, 0, stream>>>(x1, W2, nullptr, dinv,
                                                      nullptr, g2, N, 0);
    gemm_kernel<256, 32, false><<<gb, 256, 0, stream>>>(x, Ws02, bs02, nullptr,
                                                        pre2, nullptr, N, 0);
    agg_kernel<32, false><<<ab, 256, 0, stream>>>(g2, dinv, row_off, col,
                                                  b2, pre2, nullptr, nullptr, x2, N);
    // --- layer 3 + output head (fused)
    gemm_kernel<32, 16, true><<<gb, 256, 0, stream>>>(x2, W3, nullptr, dinv,
                                                      nullptr, g3, N, 0);
    gemm_kernel<256, 16, false><<<gb, 256, 0, stream>>>(x, Ws03, bs03, nullptr,
                                                        pre3, nullptr, N, 0);
    gemm_kernel<64, 16, false><<<gb, 256, 0, stream>>>(x1, Ws13, bs13, nullptr,
                                                       pre3, nullptr, N, 1);
    agg_kernel<16, true><<<ab, 256, 0, stream>>>(g3, dinv, row_off, col,
                                                 b3, pre3, Wout, bout, (float*)d_out, N);
}

// Round 3
// 668.252 us; speedup vs baseline: 2.4061x; 1.9762x over previous
//
#include <hip/hip_runtime.h>
#include <hip/hip_bf16.h>
#include <math.h>

// DenseGCN3Layer on MI355X — round 3.
// Changes vs r2:
//  * CSR build rewritten as 2-level bucket sort (no random scatter, no
//    count_deg, no serial scan): bucket_hist -> bucket_scan -> partition
//    (LDS reorder, coalesced appends) -> csr_build (per-bucket LDS sort,
//    writes row_off+dinv+col fully coalesced).
//  * GEMMs fused (x read once for W1|Ws02|Ws03; x1 once for W2|Ws13) and
//    register-tiled 2D (NPT x FPT per thread) for ~2x VALU efficiency.
//  * agg kernels unchanged from r2 (bf16 g-gather).

#define NBUCK_MAX 512
#define P1_CHUNK 8192
#define EPT 32              // edges per thread in partition (8192/256)
#define BCAP 9216           // max edges per 256-node bucket (mean 8192 + 11 sigma)

// ---------------------------------------------------------------- build

__global__ __launch_bounds__(256) void bucket_hist_kernel(
    const int* __restrict__ dst, int E, int* __restrict__ bucket_count, int nbuckets)
{
    __shared__ int lhist[NBUCK_MAX];
    for (int i = threadIdx.x; i < nbuckets; i += 256) lhist[i] = 0;
    __syncthreads();
    const int stride = gridDim.x * 256;
    for (int e = blockIdx.x * 256 + threadIdx.x; e < E; e += stride)
        atomicAdd(&lhist[dst[e] >> 8], 1);
    __syncthreads();
    for (int i = threadIdx.x; i < nbuckets; i += 256) {
        int c = lhist[i];
        if (c) atomicAdd(&bucket_count[i], c);
    }
}

__global__ __launch_bounds__(512) void bucket_scan_kernel(
    const int* __restrict__ bucket_count, int* __restrict__ bucket_base,
    int* __restrict__ bucket_cursor, int nbuckets)
{
    __shared__ int tmp[512];
    const int tid = threadIdx.x;
    int v = (tid < nbuckets) ? bucket_count[tid] : 0;
    tmp[tid] = v;
    __syncthreads();
    for (int off = 1; off < 512; off <<= 1) {
        int t = (tid >= off) ? tmp[tid - off] : 0;
        __syncthreads();
        tmp[tid] += t;
        __syncthreads();
    }
    if (tid < nbuckets) {
        int base = tmp[tid] - v;
        bucket_base[tid]   = base;
        bucket_cursor[tid] = base;
    }
}

// Partition edges into bucket regions (unordered within bucket).
// key = ((dst & 255) << 17) | src   (src < 2^17)
__global__ __launch_bounds__(256) void partition_kernel(
    const int* __restrict__ src, const int* __restrict__ dst, int E,
    int* __restrict__ bucket_cursor, unsigned int* __restrict__ keys, int nbuckets)
{
    __shared__ int hist[NBUCK_MAX];
    __shared__ int lofs[NBUCK_MAX];
    __shared__ int gbase[NBUCK_MAX];
    __shared__ int lcur[NBUCK_MAX];
    __shared__ int ssum[256];
    __shared__ unsigned int stage[P1_CHUNK];
    __shared__ int gidx[P1_CHUNK];

    const int tid = threadIdx.x;
    const int e0  = blockIdx.x * P1_CHUNK;
    const int nE  = min(P1_CHUNK, E - e0);

    for (int i = tid; i < NBUCK_MAX; i += 256) { hist[i] = 0; lcur[i] = 0; }
    __syncthreads();

    int myb[EPT];
    unsigned int mypk[EPT];
#pragma unroll
    for (int j = 0; j < EPT; ++j) {
        const int e = e0 + tid + j * 256;
        if (e < E) {
            const int d = dst[e];
            myb[j]  = d >> 8;
            mypk[j] = ((unsigned int)(d & 255) << 17) | (unsigned int)src[e];
            atomicAdd(&hist[myb[j]], 1);
        } else myb[j] = -1;
    }
    __syncthreads();

    // exclusive scan of hist[0..nbuckets) with 256 threads (2 entries each)
    int a0 = (2 * tid     < nbuckets) ? hist[2 * tid]     : 0;
    int a1 = (2 * tid + 1 < nbuckets) ? hist[2 * tid + 1] : 0;
    ssum[tid] = a0 + a1;
    __syncthreads();
    for (int off = 1; off < 256; off <<= 1) {
        int t = (tid >= off) ? ssum[tid - off] : 0;
        __syncthreads();
        ssum[tid] += t;
        __syncthreads();
    }
    const int ex = ssum[tid] - (a0 + a1);
    if (2 * tid     < nbuckets) lofs[2 * tid]     = ex;
    if (2 * tid + 1 < nbuckets) lofs[2 * tid + 1] = ex + a0;
    __syncthreads();

    // reserve global space per bucket
    for (int i = tid; i < nbuckets; i += 256)
        gbase[i] = atomicAdd(&bucket_cursor[i], hist[i]);
    __syncthreads();

    // scatter into LDS grouped by bucket
#pragma unroll
    for (int j = 0; j < EPT; ++j) {
        if (myb[j] >= 0) {
            const int b = myb[j];
            const int l = lofs[b] + atomicAdd(&lcur[b], 1);
            stage[l] = mypk[j];
            gidx[l]  = gbase[b] - lofs[b] + l;
        }
    }
    __syncthreads();

    // coalesced-run writeout
    for (int i = tid; i < nE; i += 256)
        keys[gidx[i]] = stage[i];
}

// One block per bucket: sort bucket edges by node, write row_off/dinv/col.
__global__ __launch_bounds__(256) void csr_build_kernel(
    const unsigned int* __restrict__ keys, const int* __restrict__ bucket_base,
    const int* __restrict__ bucket_count,
    int* __restrict__ row_off, float* __restrict__ dinv, int* __restrict__ col,
    int N, int E)
{
    __shared__ unsigned int inb[BCAP];
    __shared__ int outv[BCAP];
    __shared__ int hist[256];
    __shared__ int lofs[256];
    __shared__ int ssum[256];

    const int tid  = threadIdx.x;
    const int b    = blockIdx.x;
    const int base = bucket_base[b];
    const int cnt  = min(bucket_count[b], BCAP);
    const int n0   = b << 8;
    const int nn   = min(256, N - n0);

    for (int i = tid; i < cnt; i += 256) inb[i] = keys[base + i];
    hist[tid] = 0;
    __syncthreads();

    for (int i = tid; i < cnt; i += 256)
        atomicAdd(&hist[inb[i] >> 17], 1);
    __syncthreads();

    // exclusive scan of hist
    ssum[tid] = hist[tid];
    __syncthreads();
    for (int off = 1; off < 256; off <<= 1) {
        int t = (tid >= off) ? ssum[tid - off] : 0;
        __syncthreads();
        ssum[tid] += t;
        __syncthreads();
    }
    lofs[tid] = ssum[tid] - hist[tid];

    if (tid < nn) {
        row_off[n0 + tid] = base + lofs[tid];
        dinv[n0 + tid]    = rsqrtf((float)hist[tid] + 1.0f);
    }
    if (b == 0 && tid == 0) row_off[N] = E;
    __syncthreads();

    hist[tid] = 0;   // reuse as per-node cursor
    __syncthreads();

    for (int i = tid; i < cnt; i += 256) {
        const unsigned int k = inb[i];
        const int node = k >> 17;
        const int l = lofs[node] + atomicAdd(&hist[node], 1);
        outv[l] = (int)(k & 0x1FFFF);
    }
    __syncthreads();

    for (int i = tid; i < cnt; i += 256)
        col[base + i] = outv[i];
}

// ---------------------------------------------------------------- GEMM
// 2D register-tiled fp32 GEMM, 256 threads = TX(f) x TY(n), NPT nodes x FPT
// feats per thread, interleaved mapping (n = n0+ty+j*TY, f = tx+ff*TX) for
// LDS bank friendliness. Fused multi-weight staging + fused epilogues.
// MODE 0: X[.,256] @ [W1|Ws02|Ws03] -> g1(bf16,x dinv), pre2(+bs02), pre3(+bs03)
// MODE 1: X1[.,64] @ [W2|Ws13]     -> g2(bf16,x dinv), pre3 += (.+bs13)
// MODE 2: X2[.,32] @ W3            -> g3(bf16,x dinv)

template<int K, int F, int NPT, int FPT, int MODE>
__global__ __launch_bounds__(256) void gemm2_kernel(
    const float* __restrict__ X,
    const float* __restrict__ Wa, const float* __restrict__ Wb,
    const float* __restrict__ Wc,
    const float* __restrict__ biasA, const float* __restrict__ biasB,
    const float* __restrict__ dinv,
    __hip_bfloat16* __restrict__ G, float* __restrict__ P0, float* __restrict__ P1,
    int N)
{
    constexpr int TX = F / FPT;
    constexpr int TY = 256 / TX;
    constexpr int NB = TY * NPT;
    constexpr int KC = (K < 64) ? K : 64;
    constexpr int LDR = KC + 4;   // padded row (floats), keeps 16B alignment

    __shared__ __align__(16) float Xs[NB][LDR];
    __shared__ __align__(16) float Ws[F][LDR];

    const int tid = threadIdx.x;
    const int tx  = tid % TX;
    const int ty  = tid / TX;
    const int n0  = blockIdx.x * NB;

    float acc[NPT][FPT];
#pragma unroll
    for (int j = 0; j < NPT; ++j)
#pragma unroll
        for (int ff = 0; ff < FPT; ++ff) acc[j][ff] = 0.f;

    for (int kc = 0; kc < K; kc += KC) {
        // ---- stage X rows (coalesced float4)
        for (int idx = tid; idx < NB * (KC / 4); idx += 256) {
            const int n = idx / (KC / 4);
            const int q = idx % (KC / 4);
            float4 v = make_float4(0.f, 0.f, 0.f, 0.f);
            if (n0 + n < N)
                v = *reinterpret_cast<const float4*>(&X[(size_t)(n0 + n) * K + kc + 4 * q]);
            *reinterpret_cast<float4*>(&Xs[n][4 * q]) = v;
        }
        // ---- stage W transposed: Ws[f][kk], read coalesced along f
        for (int idx = tid; idx < (F / 4) * KC; idx += 256) {
            const int kk = idx / (F / 4);
            const int f0 = 4 * (idx % (F / 4));
            float4 v = make_float4(0.f, 0.f, 0.f, 0.f);
            const int krow = kc + kk;
            if (MODE == 0) {
                if (f0 < 64)       v = *reinterpret_cast<const float4*>(&Wa[(size_t)krow * 64 + f0]);
                else if (f0 < 96)  v = *reinterpret_cast<const float4*>(&Wb[(size_t)krow * 32 + (f0 - 64)]);
                else if (f0 < 112) v = *reinterpret_cast<const float4*>(&Wc[(size_t)krow * 16 + (f0 - 96)]);
            } else if (MODE == 1) {
                if (f0 < 32)       v = *reinterpret_cast<const float4*>(&Wa[(size_t)krow * 32 + f0]);
                else if (f0 < 48)  v = *reinterpret_cast<const float4*>(&Wb[(size_t)krow * 16 + (f0 - 32)]);
            } else {
                v = *reinterpret_cast<const float4*>(&Wa[(size_t)krow * 16 + f0]);
            }
            Ws[f0 + 0][kk] = v.x;
            Ws[f0 + 1][kk] = v.y;
            Ws[f0 + 2][kk] = v.z;
            Ws[f0 + 3][kk] = v.w;
        }
        __syncthreads();

#pragma unroll 2
        for (int k = 0; k < KC; k += 4) {
            float4 wv[FPT];
#pragma unroll
            for (int ff = 0; ff < FPT; ++ff)
                wv[ff] = *reinterpret_cast<const float4*>(&Ws[tx + ff * TX][k]);
#pragma unroll
            for (int j = 0; j < NPT; ++j) {
                const float4 xv = *reinterpret_cast<const float4*>(&Xs[ty + j * TY][k]);
#pragma unroll
                for (int ff = 0; ff < FPT; ++ff) {
                    acc[j][ff] = fmaf(xv.x, wv[ff].x, acc[j][ff]);
                    acc[j][ff] = fmaf(xv.y, wv[ff].y, acc[j][ff]);
                    acc[j][ff] = fmaf(xv.z, wv[ff].z, acc[j][ff]);
                    acc[j][ff] = fmaf(xv.w, wv[ff].w, acc[j][ff]);
                }
            }
        }
        __syncthreads();
    }

    // ---- epilogue
#pragma unroll
    for (int j = 0; j < NPT; ++j) {
        const int n = n0 + ty + j * TY;
        if (n >= N) continue;
        const float di = dinv[n];
#pragma unroll
        for (int ff = 0; ff < FPT; ++ff) {
            const int f = tx + ff * TX;
            const float a = acc[j][ff];
            if (MODE == 0) {
                if (f < 64)       G[(size_t)n * 64 + f] = __float2bfloat16(di * a);
                else if (f < 96)  P0[(size_t)n * 32 + (f - 64)] = a + biasA[f - 64];
                else if (f < 112) P1[(size_t)n * 16 + (f - 96)] = a + biasB[f - 96];
            } else if (MODE == 1) {
                if (f < 32)      G[(size_t)n * 32 + f] = __float2bfloat16(di * a);
                else if (f < 48) P0[(size_t)n * 16 + (f - 32)] += a + biasA[f - 32];
            } else {
                G[(size_t)n * 16 + f] = __float2bfloat16(di * a);
            }
        }
    }
}

// ---------------------------------------------------------------- aggregation
// (unchanged from r2)

template<int F, bool FINAL>
__global__ __launch_bounds__(256) void agg_kernel(
    const __hip_bfloat16* __restrict__ g, const float* __restrict__ dinv,
    const int* __restrict__ row_off, const int* __restrict__ col,
    const float* __restrict__ bias, const float* __restrict__ pre,
    const float* __restrict__ Wout, const float* __restrict__ bout,
    float* __restrict__ out, int N)
{
    const int lane = threadIdx.x & 63;
    const int wv   = threadIdx.x >> 6;
    const int i    = blockIdx.x * 4 + wv;
    if (i >= N) return;

    const int f  = lane & (F - 1);
    const int eo = lane / F;
    constexpr int EPW = 64 / F;

    float acc = 0.f;
    const int s = row_off[i];
    const int e = row_off[i + 1];
    int p = s + eo;
    for (; p + 3 * EPW < e; p += 4 * EPW) {
        const int j0 = col[p];
        const int j1 = col[p + EPW];
        const int j2 = col[p + 2 * EPW];
        const int j3 = col[p + 3 * EPW];
        const float v0 = __bfloat162float(g[(size_t)j0 * F + f]);
        const float v1 = __bfloat162float(g[(size_t)j1 * F + f]);
        const float v2 = __bfloat162float(g[(size_t)j2 * F + f]);
        const float v3 = __bfloat162float(g[(size_t)j3 * F + f]);
        acc += (v0 + v1) + (v2 + v3);
    }
    for (; p < e; p += EPW) {
        const int j = col[p];
        acc += __bfloat162float(g[(size_t)j * F + f]);
    }
#pragma unroll
    for (int off = F; off < 64; off <<= 1) acc += __shfl_xor(acc, off, 64);

    const float di = dinv[i];
    float v = di * (acc + __bfloat162float(g[(size_t)i * F + f])) + bias[f];
    if (pre) v += pre[(size_t)i * F + f];
    v = fmaxf(v, 0.f);

    if (!FINAL) {
        if (lane < F) out[(size_t)i * F + f] = v;
    } else {
        float t = v * Wout[f];
#pragma unroll
        for (int off = 1; off < F; off <<= 1) t += __shfl_xor(t, off, 64);
        if (lane == 0) out[i] = 1.0f / (1.0f + expf(-(t + bout[0])));
    }
}

// ---------------------------------------------------------------- launch

extern "C" void kernel_launch(void* const* d_in, const int* in_sizes, int n_in,
                              void* d_out, int out_size, void* d_ws, size_t ws_size,
                              hipStream_t stream)
{
    const float* x    = (const float*)d_in[0];
    const int*   edge = (const int*)d_in[1];
    const float* W1   = (const float*)d_in[2];
    const float* b1   = (const float*)d_in[3];
    const float* W2   = (const float*)d_in[4];
    const float* b2   = (const float*)d_in[5];
    const float* W3   = (const float*)d_in[6];
    const float* b3   = (const float*)d_in[7];
    const float* Ws02 = (const float*)d_in[8];
    const float* bs02 = (const float*)d_in[9];
    const float* Ws03 = (const float*)d_in[10];
    const float* bs03 = (const float*)d_in[11];
    const float* Ws13 = (const float*)d_in[12];
    const float* bs13 = (const float*)d_in[13];
    const float* Wout = (const float*)d_in[14];
    const float* bout = (const float*)d_in[15];

    const int N = in_sizes[0] / 256;
    const int E = in_sizes[1] / 2;
    const int* srcv = edge;
    const int* dstv = edge + E;
    const int nbuckets = (N + 255) >> 8;

    char* ws = (char*)d_ws;
    size_t off = 0;
    auto alloc = [&](size_t bytes) -> void* {
        void* p = ws + off;
        off += (bytes + 255) & ~(size_t)255;
        return p;
    };
    unsigned int* keys = (unsigned int*)alloc((size_t)E * 4);
    int*   col      = (int*)  alloc((size_t)E * 4);
    int*   bcount   = (int*)  alloc((size_t)NBUCK_MAX * 4);
    int*   bbase    = (int*)  alloc((size_t)NBUCK_MAX * 4);
    int*   bcursor  = (int*)  alloc((size_t)NBUCK_MAX * 4);
    int*   row_off  = (int*)  alloc((size_t)(N + 1) * 4);
    float* dinv     = (float*)alloc((size_t)N * 4);
    __hip_bfloat16* g1 = (__hip_bfloat16*)alloc((size_t)N * 64 * 2);
    __hip_bfloat16* g2 = (__hip_bfloat16*)alloc((size_t)N * 32 * 2);
    __hip_bfloat16* g3 = (__hip_bfloat16*)alloc((size_t)N * 16 * 2);
    float* x1       = (float*)alloc((size_t)N * 64 * 4);
    float* pre2     = (float*)alloc((size_t)N * 32 * 4);
    float* x2       = (float*)alloc((size_t)N * 32 * 4);
    float* pre3     = (float*)alloc((size_t)N * 16 * 4);

    // --- graph build (bucket sort)
    hipMemsetAsync(bcount, 0, (size_t)NBUCK_MAX * 4, stream);
    bucket_hist_kernel<<<1024, 256, 0, stream>>>(dstv, E, bcount, nbuckets);
    bucket_scan_kernel<<<1, 512, 0, stream>>>(bcount, bbase, bcursor, nbuckets);
    partition_kernel<<<(E + P1_CHUNK - 1) / P1_CHUNK, 256, 0, stream>>>(
        srcv, dstv, E, bcursor, keys, nbuckets);
    csr_build_kernel<<<nbuckets, 256, 0, stream>>>(
        keys, bbase, bcount, row_off, dinv, col, N, E);

    const int ab = (N + 3) / 4;

    // --- layer 1 (+ all x projections fused)
    gemm2_kernel<256, 128, 8, 8, 0><<<(N + 127) / 128, 256, 0, stream>>>(
        x, W1, Ws02, Ws03, bs02, bs03, dinv, g1, pre2, pre3, N);
    agg_kernel<64, false><<<ab, 256, 0, stream>>>(g1, dinv, row_off, col,
                                                  b1, nullptr, nullptr, nullptr, x1, N);
    // --- layer 2 (+ x1@Ws13 fused)
    gemm2_kernel<64, 64, 4, 4, 1><<<(N + 63) / 64, 256, 0, stream>>>(
        x1, W2, Ws13, nullptr, bs13, nullptr, dinv, g2, pre3, nullptr, N);
    agg_kernel<32, false><<<ab, 256, 0, stream>>>(g2, dinv, row_off, col,
                                                  b2, pre2, nullptr, nullptr, x2, N);
    // --- layer 3 + output head
    gemm2_kernel<32, 16, 4, 4, 2><<<(N + 255) / 256, 256, 0, stream>>>(
        x2, W3, nullptr, nullptr, nullptr, nullptr, dinv, g3, nullptr, nullptr, N);
    agg_kernel<16, true><<<ab, 256, 0, stream>>>(g3, dinv, row_off, col,
                                                 b3, pre3, Wout, bout, (float*)d_out, N);
}

// Round 4
// 488.880 us; speedup vs baseline: 3.2889x; 1.3669x over previous
//
#include <hip/hip_runtime.h>
#include <hip/hip_bf16.h>
#include <math.h>

// DenseGCN3Layer on MI355X — round 4.
// Changes vs r3:
//  * All GEMMs -> bf16 MFMA (mfma_f32_16x16x32_bf16, fp32 accum).
//  * Weights packed to bf16 n-major/k-contig once per call (prep kernel).
//  * x1/x2 stored bf16 straight from agg epilogues.
//  * agg kernels vectorized: 4 feats/lane (uint2 loads), 16 edges in flight.

#define NBUCK_MAX 512
#define P1_CHUNK 8192
#define EPT 32
#define BCAP 9216

typedef __attribute__((ext_vector_type(8))) short bfrag;   // 8 bf16 (4 VGPR)
typedef __attribute__((ext_vector_type(4))) float f4_t;    // acc

__device__ inline float uaf(unsigned u) { return __uint_as_float(u); }
__device__ inline ushort f2bf(float f) {
    __hip_bfloat16 b = __float2bfloat16(f);
    return *reinterpret_cast<ushort*>(&b);
}

// ---------------------------------------------------------------- build (r3)

__global__ __launch_bounds__(256) void bucket_hist_kernel(
    const int* __restrict__ dst, int E, int* __restrict__ bucket_count, int nbuckets)
{
    __shared__ int lhist[NBUCK_MAX];
    for (int i = threadIdx.x; i < nbuckets; i += 256) lhist[i] = 0;
    __syncthreads();
    const int stride = gridDim.x * 256;
    for (int e = blockIdx.x * 256 + threadIdx.x; e < E; e += stride)
        atomicAdd(&lhist[dst[e] >> 8], 1);
    __syncthreads();
    for (int i = threadIdx.x; i < nbuckets; i += 256) {
        int c = lhist[i];
        if (c) atomicAdd(&bucket_count[i], c);
    }
}

__global__ __launch_bounds__(512) void bucket_scan_kernel(
    const int* __restrict__ bucket_count, int* __restrict__ bucket_base,
    int* __restrict__ bucket_cursor, int nbuckets)
{
    __shared__ int tmp[512];
    const int tid = threadIdx.x;
    int v = (tid < nbuckets) ? bucket_count[tid] : 0;
    tmp[tid] = v;
    __syncthreads();
    for (int off = 1; off < 512; off <<= 1) {
        int t = (tid >= off) ? tmp[tid - off] : 0;
        __syncthreads();
        tmp[tid] += t;
        __syncthreads();
    }
    if (tid < nbuckets) {
        int base = tmp[tid] - v;
        bucket_base[tid]   = base;
        bucket_cursor[tid] = base;
    }
}

__global__ __launch_bounds__(256) void partition_kernel(
    const int* __restrict__ src, const int* __restrict__ dst, int E,
    int* __restrict__ bucket_cursor, unsigned int* __restrict__ keys, int nbuckets)
{
    __shared__ int hist[NBUCK_MAX];
    __shared__ int lofs[NBUCK_MAX];
    __shared__ int gbase[NBUCK_MAX];
    __shared__ int lcur[NBUCK_MAX];
    __shared__ int ssum[256];
    __shared__ unsigned int stage[P1_CHUNK];
    __shared__ int gidx[P1_CHUNK];

    const int tid = threadIdx.x;
    const int e0  = blockIdx.x * P1_CHUNK;
    const int nE  = min(P1_CHUNK, E - e0);

    for (int i = tid; i < NBUCK_MAX; i += 256) { hist[i] = 0; lcur[i] = 0; }
    __syncthreads();

    int myb[EPT];
    unsigned int mypk[EPT];
#pragma unroll
    for (int j = 0; j < EPT; ++j) {
        const int e = e0 + tid + j * 256;
        if (e < E) {
            const int d = dst[e];
            myb[j]  = d >> 8;
            mypk[j] = ((unsigned int)(d & 255) << 17) | (unsigned int)src[e];
            atomicAdd(&hist[myb[j]], 1);
        } else myb[j] = -1;
    }
    __syncthreads();

    int a0 = (2 * tid     < nbuckets) ? hist[2 * tid]     : 0;
    int a1 = (2 * tid + 1 < nbuckets) ? hist[2 * tid + 1] : 0;
    ssum[tid] = a0 + a1;
    __syncthreads();
    for (int off = 1; off < 256; off <<= 1) {
        int t = (tid >= off) ? ssum[tid - off] : 0;
        __syncthreads();
        ssum[tid] += t;
        __syncthreads();
    }
    const int ex = ssum[tid] - (a0 + a1);
    if (2 * tid     < nbuckets) lofs[2 * tid]     = ex;
    if (2 * tid + 1 < nbuckets) lofs[2 * tid + 1] = ex + a0;
    __syncthreads();

    for (int i = tid; i < nbuckets; i += 256)
        gbase[i] = atomicAdd(&bucket_cursor[i], hist[i]);
    __syncthreads();

#pragma unroll
    for (int j = 0; j < EPT; ++j) {
        if (myb[j] >= 0) {
            const int b = myb[j];
            const int l = lofs[b] + atomicAdd(&lcur[b], 1);
            stage[l] = mypk[j];
            gidx[l]  = gbase[b] - lofs[b] + l;
        }
    }
    __syncthreads();

    for (int i = tid; i < nE; i += 256)
        keys[gidx[i]] = stage[i];
}

__global__ __launch_bounds__(256) void csr_build_kernel(
    const unsigned int* __restrict__ keys, const int* __restrict__ bucket_base,
    const int* __restrict__ bucket_count,
    int* __restrict__ row_off, float* __restrict__ dinv, int* __restrict__ col,
    int N, int E)
{
    __shared__ unsigned int inb[BCAP];
    __shared__ int outv[BCAP];
    __shared__ int hist[256];
    __shared__ int lofs[256];
    __shared__ int ssum[256];

    const int tid  = threadIdx.x;
    const int b    = blockIdx.x;
    const int base = bucket_base[b];
    const int cnt  = min(bucket_count[b], BCAP);
    const int n0   = b << 8;
    const int nn   = min(256, N - n0);

    for (int i = tid; i < cnt; i += 256) inb[i] = keys[base + i];
    hist[tid] = 0;
    __syncthreads();

    for (int i = tid; i < cnt; i += 256)
        atomicAdd(&hist[inb[i] >> 17], 1);
    __syncthreads();

    ssum[tid] = hist[tid];
    __syncthreads();
    for (int off = 1; off < 256; off <<= 1) {
        int t = (tid >= off) ? ssum[tid - off] : 0;
        __syncthreads();
        ssum[tid] += t;
        __syncthreads();
    }
    lofs[tid] = ssum[tid] - hist[tid];

    if (tid < nn) {
        row_off[n0 + tid] = base + lofs[tid];
        dinv[n0 + tid]    = rsqrtf((float)hist[tid] + 1.0f);
    }
    if (b == 0 && tid == 0) row_off[N] = E;
    __syncthreads();

    hist[tid] = 0;
    __syncthreads();

    for (int i = tid; i < cnt; i += 256) {
        const unsigned int k = inb[i];
        const int node = k >> 17;
        const int l = lofs[node] + atomicAdd(&hist[node], 1);
        outv[l] = (int)(k & 0x1FFFF);
    }
    __syncthreads();

    for (int i = tid; i < cnt; i += 256)
        col[base + i] = outv[i];
}

// ---------------------------------------------------------------- weight prep
// Pack to bf16, n-major/k-contiguous (B-fragment friendly):
//  Wt0[128][256] = [W1|Ws02|Ws03|0]^T, Wt1[48][64] = [W2|Ws13]^T, Wt2[16][32] = W3^T

__global__ __launch_bounds__(256) void prep_weights_kernel(
    const float* __restrict__ W1, const float* __restrict__ Ws02,
    const float* __restrict__ Ws03, const float* __restrict__ W2,
    const float* __restrict__ Ws13, const float* __restrict__ W3,
    ushort* __restrict__ Wt0, ushort* __restrict__ Wt1, ushort* __restrict__ Wt2)
{
    int idx = blockIdx.x * 256 + threadIdx.x;
    if (idx < 32768) {
        int f = idx >> 8, k = idx & 255;
        float v = 0.f;
        if (f < 64)       v = W1[k * 64 + f];
        else if (f < 96)  v = Ws02[k * 32 + (f - 64)];
        else if (f < 112) v = Ws03[k * 16 + (f - 96)];
        Wt0[idx] = f2bf(v);
    } else if (idx < 32768 + 3072) {
        int t = idx - 32768;
        int f = t >> 6, k = t & 63;
        float v = (f < 32) ? W2[k * 32 + f] : Ws13[k * 16 + (f - 32)];
        Wt1[t] = f2bf(v);
    } else if (idx < 32768 + 3072 + 512) {
        int t = idx - 32768 - 3072;
        int f = t >> 5, k = t & 31;
        Wt2[t] = f2bf(W3[k * 16 + f]);
    }
}

// ---------------------------------------------------------------- MFMA GEMMs
// A-frag: A[m=lane&15][k=(lane>>4)*8+j]; B-frag: B[n=lane&15][k=(lane>>4)*8+j]
// C/D:    col=lane&15, row=(lane>>4)*4+reg

// MODE 0: x[N,256] fp32 (converted inline) @ Wt0 -> g1(bf16), pre2, pre3
__global__ __launch_bounds__(256) void gemm_mfma0(
    const float* __restrict__ X, const ushort* __restrict__ Wt0,
    const float* __restrict__ bs02, const float* __restrict__ bs03,
    const float* __restrict__ dinv,
    __hip_bfloat16* __restrict__ g1, float* __restrict__ pre2,
    float* __restrict__ pre3, int N)
{
    constexpr int LDB = 264;  // 256+8 bf16
    constexpr int LDA = 40;   // 32+8 bf16
    __shared__ ushort Bs[128 * LDB];  // 66 KB
    __shared__ ushort As[128 * LDA];  // 10 KB

    const int tid  = threadIdx.x;
    const int lane = tid & 63;
    const int wave = tid >> 6;
    const int n0   = blockIdx.x * 128;

    // stage all of Wt0 once (128 x 256 bf16 = 4096 uint4 chunks)
    for (int idx = tid; idx < 4096; idx += 256) {
        const int row = idx >> 5, c = idx & 31;
        *reinterpret_cast<uint4*>(&Bs[row * LDB + c * 8]) =
            *reinterpret_cast<const uint4*>(&Wt0[row * 256 + c * 8]);
    }

    f4_t acc[4][4];
#pragma unroll
    for (int a = 0; a < 4; ++a)
#pragma unroll
        for (int b = 0; b < 4; ++b) acc[a][b] = {0.f, 0.f, 0.f, 0.f};

    const int wm = wave & 1, wf = wave >> 1;

    for (int panel = 0; panel < 8; ++panel) {
        const int kc = panel * 32;
        // stage As: 128 rows x 32 k (fp32 -> bf16), 1024 float4 chunks
        for (int idx = tid; idx < 1024; idx += 256) {
            const int row = idx >> 3, q = idx & 7;
            const int n = n0 + row;
            float4 v = make_float4(0.f, 0.f, 0.f, 0.f);
            if (n < N)
                v = *reinterpret_cast<const float4*>(&X[(size_t)n * 256 + kc + q * 4]);
            ushort4 cv;
            cv.x = f2bf(v.x); cv.y = f2bf(v.y); cv.z = f2bf(v.z); cv.w = f2bf(v.w);
            *reinterpret_cast<ushort4*>(&As[row * LDA + q * 4]) = cv;
        }
        __syncthreads();

        bfrag af[4], bfr[4];
#pragma unroll
        for (int mt = 0; mt < 4; ++mt)
            af[mt] = *reinterpret_cast<const bfrag*>(
                &As[(wm * 64 + mt * 16 + (lane & 15)) * LDA + (lane >> 4) * 8]);
#pragma unroll
        for (int ft = 0; ft < 4; ++ft)
            bfr[ft] = *reinterpret_cast<const bfrag*>(
                &Bs[(wf * 64 + ft * 16 + (lane & 15)) * LDB + kc + (lane >> 4) * 8]);
#pragma unroll
        for (int mt = 0; mt < 4; ++mt)
#pragma unroll
            for (int ft = 0; ft < 4; ++ft)
                acc[mt][ft] = __builtin_amdgcn_mfma_f32_16x16x32_bf16(
                    af[mt], bfr[ft], acc[mt][ft], 0, 0, 0);
        __syncthreads();
    }

    // epilogue
#pragma unroll
    for (int mt = 0; mt < 4; ++mt) {
#pragma unroll
        for (int ft = 0; ft < 4; ++ft) {
            const int fg = wf * 64 + ft * 16 + (lane & 15);
#pragma unroll
            for (int r = 0; r < 4; ++r) {
                const int n = n0 + wm * 64 + mt * 16 + (lane >> 4) * 4 + r;
                if (n >= N) continue;
                const float a = acc[mt][ft][r];
                if (fg < 64) {
                    g1[(size_t)n * 64 + fg] = __float2bfloat16(dinv[n] * a);
                } else if (fg < 96) {
                    pre2[(size_t)n * 32 + (fg - 64)] = a + bs02[fg - 64];
                } else if (fg < 112) {
                    pre3[(size_t)n * 16 + (fg - 96)] = a + bs03[fg - 96];
                }
            }
        }
    }
}

// MODE 1: x1[N,64] bf16 @ Wt1[48][64] -> g2(bf16), pre3 += (. + bs13)
__global__ __launch_bounds__(256) void gemm_mfma1(
    const ushort* __restrict__ X1, const ushort* __restrict__ Wt1,
    const float* __restrict__ bs13, const float* __restrict__ dinv,
    __hip_bfloat16* __restrict__ g2, float* __restrict__ pre3, int N)
{
    constexpr int LDB = 72, LDA = 72;
    __shared__ ushort Bs[48 * LDB];
    __shared__ ushort As[128 * LDA];

    const int tid  = threadIdx.x;
    const int lane = tid & 63;
    const int wave = tid >> 6;
    const int n0   = blockIdx.x * 128;

    for (int idx = tid; idx < 384; idx += 256) {
        const int row = idx >> 3, c = idx & 7;
        *reinterpret_cast<uint4*>(&Bs[row * LDB + c * 8]) =
            *reinterpret_cast<const uint4*>(&Wt1[row * 64 + c * 8]);
    }
    for (int idx = tid; idx < 1024; idx += 256) {
        const int row = idx >> 3, c = idx & 7;
        const int n = n0 + row;
        uint4 v = make_uint4(0, 0, 0, 0);
        if (n < N) v = *reinterpret_cast<const uint4*>(&X1[(size_t)n * 64 + c * 8]);
        *reinterpret_cast<uint4*>(&As[row * LDA + c * 8]) = v;
    }
    __syncthreads();

    f4_t acc[2][3];
#pragma unroll
    for (int a = 0; a < 2; ++a)
#pragma unroll
        for (int b = 0; b < 3; ++b) acc[a][b] = {0.f, 0.f, 0.f, 0.f};

    const int m0 = wave * 32;
#pragma unroll
    for (int p = 0; p < 2; ++p) {
        bfrag af[2], bfr[3];
#pragma unroll
        for (int mt = 0; mt < 2; ++mt)
            af[mt] = *reinterpret_cast<const bfrag*>(
                &As[(m0 + mt * 16 + (lane & 15)) * LDA + p * 32 + (lane >> 4) * 8]);
#pragma unroll
        for (int ft = 0; ft < 3; ++ft)
            bfr[ft] = *reinterpret_cast<const bfrag*>(
                &Bs[(ft * 16 + (lane & 15)) * LDB + p * 32 + (lane >> 4) * 8]);
#pragma unroll
        for (int mt = 0; mt < 2; ++mt)
#pragma unroll
            for (int ft = 0; ft < 3; ++ft)
                acc[mt][ft] = __builtin_amdgcn_mfma_f32_16x16x32_bf16(
                    af[mt], bfr[ft], acc[mt][ft], 0, 0, 0);
    }

#pragma unroll
    for (int mt = 0; mt < 2; ++mt) {
#pragma unroll
        for (int ft = 0; ft < 3; ++ft) {
            const int fg = ft * 16 + (lane & 15);
#pragma unroll
            for (int r = 0; r < 4; ++r) {
                const int n = n0 + m0 + mt * 16 + (lane >> 4) * 4 + r;
                if (n >= N) continue;
                const float a = acc[mt][ft][r];
                if (fg < 32) {
                    g2[(size_t)n * 32 + fg] = __float2bfloat16(dinv[n] * a);
                } else {
                    pre3[(size_t)n * 16 + (fg - 32)] += a + bs13[fg - 32];
                }
            }
        }
    }
}

// MODE 2: x2[N,32] bf16 @ Wt2[16][32] -> g3(bf16)
__global__ __launch_bounds__(256) void gemm_mfma2(
    const ushort* __restrict__ X2, const ushort* __restrict__ Wt2,
    const float* __restrict__ dinv, __hip_bfloat16* __restrict__ g3, int N)
{
    constexpr int LDA = 40;
    __shared__ ushort Bs[16 * LDA];
    __shared__ ushort As[256 * LDA];

    const int tid  = threadIdx.x;
    const int lane = tid & 63;
    const int wave = tid >> 6;
    const int n0   = blockIdx.x * 256;

    for (int idx = tid; idx < 64; idx += 256) {
        const int row = idx >> 2, c = idx & 3;
        *reinterpret_cast<uint4*>(&Bs[row * LDA + c * 8]) =
            *reinterpret_cast<const uint4*>(&Wt2[row * 32 + c * 8]);
    }
    for (int idx = tid; idx < 1024; idx += 256) {
        const int row = idx >> 2, c = idx & 3;
        const int n = n0 + row;
        uint4 v = make_uint4(0, 0, 0, 0);
        if (n < N) v = *reinterpret_cast<const uint4*>(&X2[(size_t)n * 32 + c * 8]);
        *reinterpret_cast<uint4*>(&As[row * LDA + c * 8]) = v;
    }
    __syncthreads();

    f4_t acc[4];
#pragma unroll
    for (int a = 0; a < 4; ++a) acc[a] = {0.f, 0.f, 0.f, 0.f};

    const int m0 = wave * 64;
    const bfrag bfr = *reinterpret_cast<const bfrag*>(
        &Bs[(lane & 15) * LDA + (lane >> 4) * 8]);
#pragma unroll
    for (int mt = 0; mt < 4; ++mt) {
        const bfrag af = *reinterpret_cast<const bfrag*>(
            &As[(m0 + mt * 16 + (lane & 15)) * LDA + (lane >> 4) * 8]);
        acc[mt] = __builtin_amdgcn_mfma_f32_16x16x32_bf16(af, bfr, acc[mt], 0, 0, 0);
    }

    const int fg = lane & 15;
#pragma unroll
    for (int mt = 0; mt < 4; ++mt) {
#pragma unroll
        for (int r = 0; r < 4; ++r) {
            const int n = n0 + m0 + mt * 16 + (lane >> 4) * 4 + r;
            if (n >= N) continue;
            g3[(size_t)n * 16 + fg] = __float2bfloat16(dinv[n] * acc[mt][r]);
        }
    }
}

// ---------------------------------------------------------------- aggregation
// One wave/node, 4 feats per lane (uint2 = 4 bf16), FG=F/4 lanes per edge,
// EPW=64/FG edges in flight (x U unroll).
// MODE 0: out bf16, no pre. MODE 1: out bf16, pre fp32. MODE 2: final head.

template<int F, int MODE>
__global__ __launch_bounds__(256) void agg_kernel(
    const ushort* __restrict__ g, const float* __restrict__ dinv,
    const int* __restrict__ row_off, const int* __restrict__ col,
    const float* __restrict__ bias, const float* __restrict__ pre,
    const float* __restrict__ Wout, const float* __restrict__ bout,
    void* __restrict__ out, int N)
{
    constexpr int FG  = F / 4;
    constexpr int EPW = 64 / FG;
    constexpr int U   = (F == 64) ? 4 : (F == 32 ? 2 : 1);

    const int lane = threadIdx.x & 63;
    const int wv   = threadIdx.x >> 6;
    const int i    = blockIdx.x * 4 + wv;
    if (i >= N) return;

    const int fg = lane % FG;
    const int eo = lane / FG;
    const int fb = fg * 4;

    float a0 = 0.f, a1 = 0.f, a2 = 0.f, a3 = 0.f;
    const int s = row_off[i], e = row_off[i + 1];
    int p = s + eo;
    for (; p + (U - 1) * EPW < e; p += U * EPW) {
        int js[U];
#pragma unroll
        for (int u = 0; u < U; ++u) js[u] = col[p + u * EPW];
        uint2 w[U];
#pragma unroll
        for (int u = 0; u < U; ++u)
            w[u] = *reinterpret_cast<const uint2*>(&g[(size_t)js[u] * F + fb]);
#pragma unroll
        for (int u = 0; u < U; ++u) {
            a0 += uaf(w[u].x << 16);
            a1 += uaf(w[u].x & 0xffff0000u);
            a2 += uaf(w[u].y << 16);
            a3 += uaf(w[u].y & 0xffff0000u);
        }
    }
    for (; p < e; p += EPW) {
        const uint2 w0 = *reinterpret_cast<const uint2*>(&g[(size_t)col[p] * F + fb]);
        a0 += uaf(w0.x << 16);
        a1 += uaf(w0.x & 0xffff0000u);
        a2 += uaf(w0.y << 16);
        a3 += uaf(w0.y & 0xffff0000u);
    }
#pragma unroll
    for (int off = FG; off < 64; off <<= 1) {
        a0 += __shfl_xor(a0, off);
        a1 += __shfl_xor(a1, off);
        a2 += __shfl_xor(a2, off);
        a3 += __shfl_xor(a3, off);
    }

    const uint2 ws = *reinterpret_cast<const uint2*>(&g[(size_t)i * F + fb]);
    const float di = dinv[i];
    float v0 = di * (a0 + uaf(ws.x << 16))        + bias[fb + 0];
    float v1 = di * (a1 + uaf(ws.x & 0xffff0000u)) + bias[fb + 1];
    float v2 = di * (a2 + uaf(ws.y << 16))        + bias[fb + 2];
    float v3 = di * (a3 + uaf(ws.y & 0xffff0000u)) + bias[fb + 3];
    if (MODE != 0) {
        const float4 pv = *reinterpret_cast<const float4*>(&pre[(size_t)i * F + fb]);
        v0 += pv.x; v1 += pv.y; v2 += pv.z; v3 += pv.w;
    }
    v0 = fmaxf(v0, 0.f); v1 = fmaxf(v1, 0.f);
    v2 = fmaxf(v2, 0.f); v3 = fmaxf(v3, 0.f);

    if (MODE != 2) {
        if (lane < FG) {
            uint2 o;
            o.x = (unsigned)f2bf(v0) | ((unsigned)f2bf(v1) << 16);
            o.y = (unsigned)f2bf(v2) | ((unsigned)f2bf(v3) << 16);
            *reinterpret_cast<uint2*>(&((ushort*)out)[(size_t)i * F + fb]) = o;
        }
    } else {
        float t = v0 * Wout[fb] + v1 * Wout[fb + 1] +
                  v2 * Wout[fb + 2] + v3 * Wout[fb + 3];
        t += __shfl_xor(t, 1);
        t += __shfl_xor(t, 2);
        if (lane == 0)
            ((float*)out)[i] = 1.0f / (1.0f + expf(-(t + bout[0])));
    }
}

// ---------------------------------------------------------------- launch

extern "C" void kernel_launch(void* const* d_in, const int* in_sizes, int n_in,
                              void* d_out, int out_size, void* d_ws, size_t ws_size,
                              hipStream_t stream)
{
    const float* x    = (const float*)d_in[0];
    const int*   edge = (const int*)d_in[1];
    const float* W1   = (const float*)d_in[2];
    const float* b1   = (const float*)d_in[3];
    const float* W2   = (const float*)d_in[4];
    const float* b2   = (const float*)d_in[5];
    const float* W3   = (const float*)d_in[6];
    const float* b3   = (const float*)d_in[7];
    const float* Ws02 = (const float*)d_in[8];
    const float* bs02 = (const float*)d_in[9];
    const float* Ws03 = (const float*)d_in[10];
    const float* bs03 = (const float*)d_in[11];
    const float* Ws13 = (const float*)d_in[12];
    const float* bs13 = (const float*)d_in[13];
    const float* Wout = (const float*)d_in[14];
    const float* bout = (const float*)d_in[15];

    const int N = in_sizes[0] / 256;
    const int E = in_sizes[1] / 2;
    const int* srcv = edge;
    const int* dstv = edge + E;
    const int nbuckets = (N + 255) >> 8;

    char* ws = (char*)d_ws;
    size_t off = 0;
    auto alloc = [&](size_t bytes) -> void* {
        void* p = ws + off;
        off += (bytes + 255) & ~(size_t)255;
        return p;
    };
    unsigned int* keys = (unsigned int*)alloc((size_t)E * 4);
    int*   col      = (int*)  alloc((size_t)E * 4);
    int*   bcount   = (int*)  alloc((size_t)NBUCK_MAX * 4);
    int*   bbase    = (int*)  alloc((size_t)NBUCK_MAX * 4);
    int*   bcursor  = (int*)  alloc((size_t)NBUCK_MAX * 4);
    int*   row_off  = (int*)  alloc((size_t)(N + 1) * 4);
    float* dinv     = (float*)alloc((size_t)N * 4);
    ushort* Wt0     = (ushort*)alloc((size_t)128 * 256 * 2);
    ushort* Wt1     = (ushort*)alloc((size_t)48 * 64 * 2);
    ushort* Wt2     = (ushort*)alloc((size_t)16 * 32 * 2);
    ushort* g1      = (ushort*)alloc((size_t)N * 64 * 2);
    ushort* x1      = (ushort*)alloc((size_t)N * 64 * 2);
    ushort* g2      = (ushort*)alloc((size_t)N * 32 * 2);
    ushort* x2      = (ushort*)alloc((size_t)N * 32 * 2);
    ushort* g3      = (ushort*)alloc((size_t)N * 16 * 2);
    float* pre2     = (float*)alloc((size_t)N * 32 * 4);
    float* pre3     = (float*)alloc((size_t)N * 16 * 4);

    // --- weight prep + graph build
    prep_weights_kernel<<<142, 256, 0, stream>>>(W1, Ws02, Ws03, W2, Ws13, W3,
                                                 Wt0, Wt1, Wt2);
    hipMemsetAsync(bcount, 0, (size_t)NBUCK_MAX * 4, stream);
    bucket_hist_kernel<<<1024, 256, 0, stream>>>(dstv, E, bcount, nbuckets);
    bucket_scan_kernel<<<1, 512, 0, stream>>>(bcount, bbase, bcursor, nbuckets);
    partition_kernel<<<(E + P1_CHUNK - 1) / P1_CHUNK, 256, 0, stream>>>(
        srcv, dstv, E, bcursor, keys, nbuckets);
    csr_build_kernel<<<nbuckets, 256, 0, stream>>>(
        keys, bbase, bcount, row_off, dinv, col, N, E);

    const int ab = (N + 3) / 4;

    // --- layer 1 (+ all x projections fused)
    gemm_mfma0<<<(N + 127) / 128, 256, 0, stream>>>(
        x, Wt0, bs02, bs03, dinv, (__hip_bfloat16*)g1, pre2, pre3, N);
    agg_kernel<64, 0><<<ab, 256, 0, stream>>>(g1, dinv, row_off, col,
                                              b1, nullptr, nullptr, nullptr, x1, N);
    // --- layer 2 (+ x1@Ws13 fused)
    gemm_mfma1<<<(N + 127) / 128, 256, 0, stream>>>(
        x1, Wt1, bs13, dinv, (__hip_bfloat16*)g2, pre3, N);
    agg_kernel<32, 1><<<ab, 256, 0, stream>>>(g2, dinv, row_off, col,
                                              b2, pre2, nullptr, nullptr, x2, N);
    // --- layer 3 + output head
    gemm_mfma2<<<(N + 255) / 256, 256, 0, stream>>>(
        x2, Wt2, dinv, (__hip_bfloat16*)g3, N);
    agg_kernel<16, 2><<<ab, 256, 0, stream>>>(g3, dinv, row_off, col,
                                              b3, pre3, Wout, bout, d_out, N);
}

// Round 5
// 477.873 us; speedup vs baseline: 3.3647x; 1.0230x over previous
//
#include <hip/hip_runtime.h>
#include <hip/hip_bf16.h>
#include <math.h>

// DenseGCN3Layer on MI355X — round 5.
// Changes vs r4:
//  * gemm_mfma0: removed 66KB Bs LDS tile (B-frags loaded from global, L2-hot),
//    double-buffered As staging with register prefetch, __launch_bounds__(256,4).
//    LDS 78KB -> 20KB, occupancy 2 -> ~4 blocks/CU.

#define NBUCK_MAX 512
#define P1_CHUNK 8192
#define EPT 32
#define BCAP 9216

typedef __attribute__((ext_vector_type(8))) short bfrag;   // 8 bf16 (4 VGPR)
typedef __attribute__((ext_vector_type(4))) float f4_t;    // acc

__device__ inline float uaf(unsigned u) { return __uint_as_float(u); }
__device__ inline ushort f2bf(float f) {
    __hip_bfloat16 b = __float2bfloat16(f);
    return *reinterpret_cast<ushort*>(&b);
}

// ---------------------------------------------------------------- build (r3)

__global__ __launch_bounds__(256) void bucket_hist_kernel(
    const int* __restrict__ dst, int E, int* __restrict__ bucket_count, int nbuckets)
{
    __shared__ int lhist[NBUCK_MAX];
    for (int i = threadIdx.x; i < nbuckets; i += 256) lhist[i] = 0;
    __syncthreads();
    const int stride = gridDim.x * 256;
    for (int e = blockIdx.x * 256 + threadIdx.x; e < E; e += stride)
        atomicAdd(&lhist[dst[e] >> 8], 1);
    __syncthreads();
    for (int i = threadIdx.x; i < nbuckets; i += 256) {
        int c = lhist[i];
        if (c) atomicAdd(&bucket_count[i], c);
    }
}

__global__ __launch_bounds__(512) void bucket_scan_kernel(
    const int* __restrict__ bucket_count, int* __restrict__ bucket_base,
    int* __restrict__ bucket_cursor, int nbuckets)
{
    __shared__ int tmp[512];
    const int tid = threadIdx.x;
    int v = (tid < nbuckets) ? bucket_count[tid] : 0;
    tmp[tid] = v;
    __syncthreads();
    for (int off = 1; off < 512; off <<= 1) {
        int t = (tid >= off) ? tmp[tid - off] : 0;
        __syncthreads();
        tmp[tid] += t;
        __syncthreads();
    }
    if (tid < nbuckets) {
        int base = tmp[tid] - v;
        bucket_base[tid]   = base;
        bucket_cursor[tid] = base;
    }
}

__global__ __launch_bounds__(256) void partition_kernel(
    const int* __restrict__ src, const int* __restrict__ dst, int E,
    int* __restrict__ bucket_cursor, unsigned int* __restrict__ keys, int nbuckets)
{
    __shared__ int hist[NBUCK_MAX];
    __shared__ int lofs[NBUCK_MAX];
    __shared__ int gbase[NBUCK_MAX];
    __shared__ int lcur[NBUCK_MAX];
    __shared__ int ssum[256];
    __shared__ unsigned int stage[P1_CHUNK];
    __shared__ int gidx[P1_CHUNK];

    const int tid = threadIdx.x;
    const int e0  = blockIdx.x * P1_CHUNK;
    const int nE  = min(P1_CHUNK, E - e0);

    for (int i = tid; i < NBUCK_MAX; i += 256) { hist[i] = 0; lcur[i] = 0; }
    __syncthreads();

    int myb[EPT];
    unsigned int mypk[EPT];
#pragma unroll
    for (int j = 0; j < EPT; ++j) {
        const int e = e0 + tid + j * 256;
        if (e < E) {
            const int d = dst[e];
            myb[j]  = d >> 8;
            mypk[j] = ((unsigned int)(d & 255) << 17) | (unsigned int)src[e];
            atomicAdd(&hist[myb[j]], 1);
        } else myb[j] = -1;
    }
    __syncthreads();

    int a0 = (2 * tid     < nbuckets) ? hist[2 * tid]     : 0;
    int a1 = (2 * tid + 1 < nbuckets) ? hist[2 * tid + 1] : 0;
    ssum[tid] = a0 + a1;
    __syncthreads();
    for (int off = 1; off < 256; off <<= 1) {
        int t = (tid >= off) ? ssum[tid - off] : 0;
        __syncthreads();
        ssum[tid] += t;
        __syncthreads();
    }
    const int ex = ssum[tid] - (a0 + a1);
    if (2 * tid     < nbuckets) lofs[2 * tid]     = ex;
    if (2 * tid + 1 < nbuckets) lofs[2 * tid + 1] = ex + a0;
    __syncthreads();

    for (int i = tid; i < nbuckets; i += 256)
        gbase[i] = atomicAdd(&bucket_cursor[i], hist[i]);
    __syncthreads();

#pragma unroll
    for (int j = 0; j < EPT; ++j) {
        if (myb[j] >= 0) {
            const int b = myb[j];
            const int l = lofs[b] + atomicAdd(&lcur[b], 1);
            stage[l] = mypk[j];
            gidx[l]  = gbase[b] - lofs[b] + l;
        }
    }
    __syncthreads();

    for (int i = tid; i < nE; i += 256)
        keys[gidx[i]] = stage[i];
}

__global__ __launch_bounds__(256) void csr_build_kernel(
    const unsigned int* __restrict__ keys, const int* __restrict__ bucket_base,
    const int* __restrict__ bucket_count,
    int* __restrict__ row_off, float* __restrict__ dinv, int* __restrict__ col,
    int N, int E)
{
    __shared__ unsigned int inb[BCAP];
    __shared__ int outv[BCAP];
    __shared__ int hist[256];
    __shared__ int lofs[256];
    __shared__ int ssum[256];

    const int tid  = threadIdx.x;
    const int b    = blockIdx.x;
    const int base = bucket_base[b];
    const int cnt  = min(bucket_count[b], BCAP);
    const int n0   = b << 8;
    const int nn   = min(256, N - n0);

    for (int i = tid; i < cnt; i += 256) inb[i] = keys[base + i];
    hist[tid] = 0;
    __syncthreads();

    for (int i = tid; i < cnt; i += 256)
        atomicAdd(&hist[inb[i] >> 17], 1);
    __syncthreads();

    ssum[tid] = hist[tid];
    __syncthreads();
    for (int off = 1; off < 256; off <<= 1) {
        int t = (tid >= off) ? ssum[tid - off] : 0;
        __syncthreads();
        ssum[tid] += t;
        __syncthreads();
    }
    lofs[tid] = ssum[tid] - hist[tid];

    if (tid < nn) {
        row_off[n0 + tid] = base + lofs[tid];
        dinv[n0 + tid]    = rsqrtf((float)hist[tid] + 1.0f);
    }
    if (b == 0 && tid == 0) row_off[N] = E;
    __syncthreads();

    hist[tid] = 0;
    __syncthreads();

    for (int i = tid; i < cnt; i += 256) {
        const unsigned int k = inb[i];
        const int node = k >> 17;
        const int l = lofs[node] + atomicAdd(&hist[node], 1);
        outv[l] = (int)(k & 0x1FFFF);
    }
    __syncthreads();

    for (int i = tid; i < cnt; i += 256)
        col[base + i] = outv[i];
}

// ---------------------------------------------------------------- weight prep

__global__ __launch_bounds__(256) void prep_weights_kernel(
    const float* __restrict__ W1, const float* __restrict__ Ws02,
    const float* __restrict__ Ws03, const float* __restrict__ W2,
    const float* __restrict__ Ws13, const float* __restrict__ W3,
    ushort* __restrict__ Wt0, ushort* __restrict__ Wt1, ushort* __restrict__ Wt2)
{
    int idx = blockIdx.x * 256 + threadIdx.x;
    if (idx < 32768) {
        int f = idx >> 8, k = idx & 255;
        float v = 0.f;
        if (f < 64)       v = W1[k * 64 + f];
        else if (f < 96)  v = Ws02[k * 32 + (f - 64)];
        else if (f < 112) v = Ws03[k * 16 + (f - 96)];
        Wt0[idx] = f2bf(v);
    } else if (idx < 32768 + 3072) {
        int t = idx - 32768;
        int f = t >> 6, k = t & 63;
        float v = (f < 32) ? W2[k * 32 + f] : Ws13[k * 16 + (f - 32)];
        Wt1[t] = f2bf(v);
    } else if (idx < 32768 + 3072 + 512) {
        int t = idx - 32768 - 3072;
        int f = t >> 5, k = t & 31;
        Wt2[t] = f2bf(W3[k * 16 + f]);
    }
}

// ---------------------------------------------------------------- MFMA GEMMs
// A-frag: A[m=lane&15][k=(lane>>4)*8+j]; B-frag: B[n=lane&15][k=(lane>>4)*8+j]
// C/D:    col=lane&15, row=(lane>>4)*4+reg

// MODE 0: x[N,256] fp32 @ Wt0[128][256] -> g1(bf16), pre2, pre3
// No LDS for B (global, L2-hot). Double-buffered As with register prefetch.
__global__ __launch_bounds__(256, 4) void gemm_mfma0(
    const float* __restrict__ X, const ushort* __restrict__ Wt0,
    const float* __restrict__ bs02, const float* __restrict__ bs03,
    const float* __restrict__ dinv,
    __hip_bfloat16* __restrict__ g1, float* __restrict__ pre2,
    float* __restrict__ pre3, int N)
{
    constexpr int LDA = 40;   // 32+8 bf16
    __shared__ ushort As[2][128 * LDA];   // 2 x 10 KB

    const int tid  = threadIdx.x;
    const int lane = tid & 63;
    const int wave = tid >> 6;
    const int n0   = blockIdx.x * 128;

    // staging split: each thread owns 4 float4 chunks (row = tid>>1 stays
    // fixed, q = (tid&1)*4 + j), i.e. rows interleaved for coalescing.
    const int srow = tid >> 1;          // 0..127
    const int sq   = (tid & 1) * 4;     // 0 or 4 (float4 index within row)
    const float* xrow = (n0 + srow < N) ? &X[(size_t)(n0 + srow) * 256] : nullptr;

    float4 pf[4];
    // prefetch panel 0
#pragma unroll
    for (int j = 0; j < 4; ++j)
        pf[j] = xrow ? *reinterpret_cast<const float4*>(&xrow[(sq + j) * 4])
                     : make_float4(0.f, 0.f, 0.f, 0.f);

    f4_t acc[4][4];
#pragma unroll
    for (int a = 0; a < 4; ++a)
#pragma unroll
        for (int b = 0; b < 4; ++b) acc[a][b] = {0.f, 0.f, 0.f, 0.f};

    const int wm = wave & 1, wf = wave >> 1;
    const int mrow = (lane & 15);
    const int kq   = (lane >> 4) * 8;

    // write panel 0 into buf 0
    {
        ushort* dst = &As[0][srow * LDA + sq * 4];
#pragma unroll
        for (int j = 0; j < 4; ++j) {
            ushort4 cv;
            cv.x = f2bf(pf[j].x); cv.y = f2bf(pf[j].y);
            cv.z = f2bf(pf[j].z); cv.w = f2bf(pf[j].w);
            *reinterpret_cast<ushort4*>(&dst[j * 4]) = cv;
        }
    }
    __syncthreads();

    for (int panel = 0; panel < 8; ++panel) {
        const int kc = panel * 32;
        const int buf = panel & 1;

        // issue next panel's global loads (latency overlapped with MFMAs)
        if (panel < 7) {
#pragma unroll
            for (int j = 0; j < 4; ++j)
                pf[j] = xrow ? *reinterpret_cast<const float4*>(
                                   &xrow[(panel + 1) * 32 + (sq + j) * 4])
                             : make_float4(0.f, 0.f, 0.f, 0.f);
        }

        // B fragments from global (identical across blocks -> L1/L2 hit)
        bfrag bfr[4];
#pragma unroll
        for (int ft = 0; ft < 4; ++ft) {
            const uint4 raw = *reinterpret_cast<const uint4*>(
                &Wt0[(size_t)(wf * 64 + ft * 16 + mrow) * 256 + kc + kq]);
            bfr[ft] = *reinterpret_cast<const bfrag*>(&raw);
        }
        bfrag af[4];
#pragma unroll
        for (int mt = 0; mt < 4; ++mt)
            af[mt] = *reinterpret_cast<const bfrag*>(
                &As[buf][(wm * 64 + mt * 16 + mrow) * LDA + kq]);
#pragma unroll
        for (int mt = 0; mt < 4; ++mt)
#pragma unroll
            for (int ft = 0; ft < 4; ++ft)
                acc[mt][ft] = __builtin_amdgcn_mfma_f32_16x16x32_bf16(
                    af[mt], bfr[ft], acc[mt][ft], 0, 0, 0);

        // write next panel into the other buffer
        if (panel < 7) {
            ushort* dst = &As[1 - buf][srow * LDA + sq * 4];
#pragma unroll
            for (int j = 0; j < 4; ++j) {
                ushort4 cv;
                cv.x = f2bf(pf[j].x); cv.y = f2bf(pf[j].y);
                cv.z = f2bf(pf[j].z); cv.w = f2bf(pf[j].w);
                *reinterpret_cast<ushort4*>(&dst[j * 4]) = cv;
            }
            __syncthreads();
        }
    }

    // epilogue
#pragma unroll
    for (int mt = 0; mt < 4; ++mt) {
#pragma unroll
        for (int ft = 0; ft < 4; ++ft) {
            const int fg = wf * 64 + ft * 16 + mrow;
#pragma unroll
            for (int r = 0; r < 4; ++r) {
                const int n = n0 + wm * 64 + mt * 16 + (lane >> 4) * 4 + r;
                if (n >= N) continue;
                const float a = acc[mt][ft][r];
                if (fg < 64) {
                    g1[(size_t)n * 64 + fg] = __float2bfloat16(dinv[n] * a);
                } else if (fg < 96) {
                    pre2[(size_t)n * 32 + (fg - 64)] = a + bs02[fg - 64];
                } else if (fg < 112) {
                    pre3[(size_t)n * 16 + (fg - 96)] = a + bs03[fg - 96];
                }
            }
        }
    }
}

// MODE 1: x1[N,64] bf16 @ Wt1[48][64] -> g2(bf16), pre3 += (. + bs13)
__global__ __launch_bounds__(256) void gemm_mfma1(
    const ushort* __restrict__ X1, const ushort* __restrict__ Wt1,
    const float* __restrict__ bs13, const float* __restrict__ dinv,
    __hip_bfloat16* __restrict__ g2, float* __restrict__ pre3, int N)
{
    constexpr int LDA = 72;
    __shared__ ushort As[128 * LDA];

    const int tid  = threadIdx.x;
    const int lane = tid & 63;
    const int wave = tid >> 6;
    const int n0   = blockIdx.x * 128;

    for (int idx = tid; idx < 1024; idx += 256) {
        const int row = idx >> 3, c = idx & 7;
        const int n = n0 + row;
        uint4 v = make_uint4(0, 0, 0, 0);
        if (n < N) v = *reinterpret_cast<const uint4*>(&X1[(size_t)n * 64 + c * 8]);
        *reinterpret_cast<uint4*>(&As[row * LDA + c * 8]) = v;
    }
    __syncthreads();

    f4_t acc[2][3];
#pragma unroll
    for (int a = 0; a < 2; ++a)
#pragma unroll
        for (int b = 0; b < 3; ++b) acc[a][b] = {0.f, 0.f, 0.f, 0.f};

    const int m0 = wave * 32;
    const int mrow = lane & 15;
    const int kq   = (lane >> 4) * 8;
#pragma unroll
    for (int p = 0; p < 2; ++p) {
        bfrag af[2], bfr[3];
#pragma unroll
        for (int mt = 0; mt < 2; ++mt)
            af[mt] = *reinterpret_cast<const bfrag*>(
                &As[(m0 + mt * 16 + mrow) * LDA + p * 32 + kq]);
#pragma unroll
        for (int ft = 0; ft < 3; ++ft) {
            const uint4 raw = *reinterpret_cast<const uint4*>(
                &Wt1[(size_t)(ft * 16 + mrow) * 64 + p * 32 + kq]);
            bfr[ft] = *reinterpret_cast<const bfrag*>(&raw);
        }
#pragma unroll
        for (int mt = 0; mt < 2; ++mt)
#pragma unroll
            for (int ft = 0; ft < 3; ++ft)
                acc[mt][ft] = __builtin_amdgcn_mfma_f32_16x16x32_bf16(
                    af[mt], bfr[ft], acc[mt][ft], 0, 0, 0);
    }

#pragma unroll
    for (int mt = 0; mt < 2; ++mt) {
#pragma unroll
        for (int ft = 0; ft < 3; ++ft) {
            const int fg = ft * 16 + mrow;
#pragma unroll
            for (int r = 0; r < 4; ++r) {
                const int n = n0 + m0 + mt * 16 + (lane >> 4) * 4 + r;
                if (n >= N) continue;
                const float a = acc[mt][ft][r];
                if (fg < 32) {
                    g2[(size_t)n * 32 + fg] = __float2bfloat16(dinv[n] * a);
                } else {
                    pre3[(size_t)n * 16 + (fg - 32)] += a + bs13[fg - 32];
                }
            }
        }
    }
}

// MODE 2: x2[N,32] bf16 @ Wt2[16][32] -> g3(bf16)
__global__ __launch_bounds__(256) void gemm_mfma2(
    const ushort* __restrict__ X2, const ushort* __restrict__ Wt2,
    const float* __restrict__ dinv, __hip_bfloat16* __restrict__ g3, int N)
{
    constexpr int LDA = 40;
    __shared__ ushort As[256 * LDA];

    const int tid  = threadIdx.x;
    const int lane = tid & 63;
    const int wave = tid >> 6;
    const int n0   = blockIdx.x * 256;

    for (int idx = tid; idx < 1024; idx += 256) {
        const int row = idx >> 2, c = idx & 3;
        const int n = n0 + row;
        uint4 v = make_uint4(0, 0, 0, 0);
        if (n < N) v = *reinterpret_cast<const uint4*>(&X2[(size_t)n * 32 + c * 8]);
        *reinterpret_cast<uint4*>(&As[row * LDA + c * 8]) = v;
    }
    __syncthreads();

    f4_t acc[4];
#pragma unroll
    for (int a = 0; a < 4; ++a) acc[a] = {0.f, 0.f, 0.f, 0.f};

    const int m0 = wave * 64;
    const int mrow = lane & 15;
    const int kq   = (lane >> 4) * 8;
    const uint4 raw = *reinterpret_cast<const uint4*>(&Wt2[(size_t)mrow * 32 + kq]);
    const bfrag bfr = *reinterpret_cast<const bfrag*>(&raw);
#pragma unroll
    for (int mt = 0; mt < 4; ++mt) {
        const bfrag af = *reinterpret_cast<const bfrag*>(
            &As[(m0 + mt * 16 + mrow) * LDA + kq]);
        acc[mt] = __builtin_amdgcn_mfma_f32_16x16x32_bf16(af, bfr, acc[mt], 0, 0, 0);
    }

#pragma unroll
    for (int mt = 0; mt < 4; ++mt) {
#pragma unroll
        for (int r = 0; r < 4; ++r) {
            const int n = n0 + m0 + mt * 16 + (lane >> 4) * 4 + r;
            if (n >= N) continue;
            g3[(size_t)n * 16 + mrow] = __float2bfloat16(dinv[n] * acc[mt][r]);
        }
    }
}

// ---------------------------------------------------------------- aggregation

template<int F, int MODE>
__global__ __launch_bounds__(256) void agg_kernel(
    const ushort* __restrict__ g, const float* __restrict__ dinv,
    const int* __restrict__ row_off, const int* __restrict__ col,
    const float* __restrict__ bias, const float* __restrict__ pre,
    const float* __restrict__ Wout, const float* __restrict__ bout,
    void* __restrict__ out, int N)
{
    constexpr int FG  = F / 4;
    constexpr int EPW = 64 / FG;
    constexpr int U   = (F == 64) ? 4 : (F == 32 ? 2 : 1);

    const int lane = threadIdx.x & 63;
    const int wv   = threadIdx.x >> 6;
    const int i    = blockIdx.x * 4 + wv;
    if (i >= N) return;

    const int fg = lane % FG;
    const int eo = lane / FG;
    const int fb = fg * 4;

    float a0 = 0.f, a1 = 0.f, a2 = 0.f, a3 = 0.f;
    const int s = row_off[i], e = row_off[i + 1];
    int p = s + eo;
    for (; p + (U - 1) * EPW < e; p += U * EPW) {
        int js[U];
#pragma unroll
        for (int u = 0; u < U; ++u) js[u] = col[p + u * EPW];
        uint2 w[U];
#pragma unroll
        for (int u = 0; u < U; ++u)
            w[u] = *reinterpret_cast<const uint2*>(&g[(size_t)js[u] * F + fb]);
#pragma unroll
        for (int u = 0; u < U; ++u) {
            a0 += uaf(w[u].x << 16);
            a1 += uaf(w[u].x & 0xffff0000u);
            a2 += uaf(w[u].y << 16);
            a3 += uaf(w[u].y & 0xffff0000u);
        }
    }
    for (; p < e; p += EPW) {
        const uint2 w0 = *reinterpret_cast<const uint2*>(&g[(size_t)col[p] * F + fb]);
        a0 += uaf(w0.x << 16);
        a1 += uaf(w0.x & 0xffff0000u);
        a2 += uaf(w0.y << 16);
        a3 += uaf(w0.y & 0xffff0000u);
    }
#pragma unroll
    for (int off = FG; off < 64; off <<= 1) {
        a0 += __shfl_xor(a0, off);
        a1 += __shfl_xor(a1, off);
        a2 += __shfl_xor(a2, off);
        a3 += __shfl_xor(a3, off);
    }

    const uint2 ws = *reinterpret_cast<const uint2*>(&g[(size_t)i * F + fb]);
    const float di = dinv[i];
    float v0 = di * (a0 + uaf(ws.x << 16))        + bias[fb + 0];
    float v1 = di * (a1 + uaf(ws.x & 0xffff0000u)) + bias[fb + 1];
    float v2 = di * (a2 + uaf(ws.y << 16))        + bias[fb + 2];
    float v3 = di * (a3 + uaf(ws.y & 0xffff0000u)) + bias[fb + 3];
    if (MODE != 0) {
        const float4 pv = *reinterpret_cast<const float4*>(&pre[(size_t)i * F + fb]);
        v0 += pv.x; v1 += pv.y; v2 += pv.z; v3 += pv.w;
    }
    v0 = fmaxf(v0, 0.f); v1 = fmaxf(v1, 0.f);
    v2 = fmaxf(v2, 0.f); v3 = fmaxf(v3, 0.f);

    if (MODE != 2) {
        if (lane < FG) {
            uint2 o;
            o.x = (unsigned)f2bf(v0) | ((unsigned)f2bf(v1) << 16);
            o.y = (unsigned)f2bf(v2) | ((unsigned)f2bf(v3) << 16);
            *reinterpret_cast<uint2*>(&((ushort*)out)[(size_t)i * F + fb]) = o;
        }
    } else {
        float t = v0 * Wout[fb] + v1 * Wout[fb + 1] +
                  v2 * Wout[fb + 2] + v3 * Wout[fb + 3];
        t += __shfl_xor(t, 1);
        t += __shfl_xor(t, 2);
        if (lane == 0)
            ((float*)out)[i] = 1.0f / (1.0f + expf(-(t + bout[0])));
    }
}

// ---------------------------------------------------------------- launch

extern "C" void kernel_launch(void* const* d_in, const int* in_sizes, int n_in,
                              void* d_out, int out_size, void* d_ws, size_t ws_size,
                              hipStream_t stream)
{
    const float* x    = (const float*)d_in[0];
    const int*   edge = (const int*)d_in[1];
    const float* W1   = (const float*)d_in[2];
    const float* b1   = (const float*)d_in[3];
    const float* W2   = (const float*)d_in[4];
    const float* b2   = (const float*)d_in[5];
    const float* W3   = (const float*)d_in[6];
    const float* b3   = (const float*)d_in[7];
    const float* Ws02 = (const float*)d_in[8];
    const float* bs02 = (const float*)d_in[9];
    const float* Ws03 = (const float*)d_in[10];
    const float* bs03 = (const float*)d_in[11];
    const float* Ws13 = (const float*)d_in[12];
    const float* bs13 = (const float*)d_in[13];
    const float* Wout = (const float*)d_in[14];
    const float* bout = (const float*)d_in[15];

    const int N = in_sizes[0] / 256;
    const int E = in_sizes[1] / 2;
    const int* srcv = edge;
    const int* dstv = edge + E;
    const int nbuckets = (N + 255) >> 8;

    char* ws = (char*)d_ws;
    size_t off = 0;
    auto alloc = [&](size_t bytes) -> void* {
        void* p = ws + off;
        off += (bytes + 255) & ~(size_t)255;
        return p;
    };
    unsigned int* keys = (unsigned int*)alloc((size_t)E * 4);
    int*   col      = (int*)  alloc((size_t)E * 4);
    int*   bcount   = (int*)  alloc((size_t)NBUCK_MAX * 4);
    int*   bbase    = (int*)  alloc((size_t)NBUCK_MAX * 4);
    int*   bcursor  = (int*)  alloc((size_t)NBUCK_MAX * 4);
    int*   row_off  = (int*)  alloc((size_t)(N + 1) * 4);
    float* dinv     = (float*)alloc((size_t)N * 4);
    ushort* Wt0     = (ushort*)alloc((size_t)128 * 256 * 2);
    ushort* Wt1     = (ushort*)alloc((size_t)48 * 64 * 2);
    ushort* Wt2     = (ushort*)alloc((size_t)16 * 32 * 2);
    ushort* g1      = (ushort*)alloc((size_t)N * 64 * 2);
    ushort* x1      = (ushort*)alloc((size_t)N * 64 * 2);
    ushort* g2      = (ushort*)alloc((size_t)N * 32 * 2);
    ushort* x2      = (ushort*)alloc((size_t)N * 32 * 2);
    ushort* g3      = (ushort*)alloc((size_t)N * 16 * 2);
    float* pre2     = (float*)alloc((size_t)N * 32 * 4);
    float* pre3     = (float*)alloc((size_t)N * 16 * 4);

    // --- weight prep + graph build
    prep_weights_kernel<<<142, 256, 0, stream>>>(W1, Ws02, Ws03, W2, Ws13, W3,
                                                 Wt0, Wt1, Wt2);
    hipMemsetAsync(bcount, 0, (size_t)NBUCK_MAX * 4, stream);
    bucket_hist_kernel<<<1024, 256, 0, stream>>>(dstv, E, bcount, nbuckets);
    bucket_scan_kernel<<<1, 512, 0, stream>>>(bcount, bbase, bcursor, nbuckets);
    partition_kernel<<<(E + P1_CHUNK - 1) / P1_CHUNK, 256, 0, stream>>>(
        srcv, dstv, E, bcursor, keys, nbuckets);
    csr_build_kernel<<<nbuckets, 256, 0, stream>>>(
        keys, bbase, bcount, row_off, dinv, col, N, E);

    const int ab = (N + 3) / 4;

    // --- layer 1 (+ all x projections fused)
    gemm_mfma0<<<(N + 127) / 128, 256, 0, stream>>>(
        x, Wt0, bs02, bs03, dinv, (__hip_bfloat16*)g1, pre2, pre3, N);
    agg_kernel<64, 0><<<ab, 256, 0, stream>>>(g1, dinv, row_off, col,
                                              b1, nullptr, nullptr, nullptr, x1, N);
    // --- layer 2 (+ x1@Ws13 fused)
    gemm_mfma1<<<(N + 127) / 128, 256, 0, stream>>>(
        x1, Wt1, bs13, dinv, (__hip_bfloat16*)g2, pre3, N);
    agg_kernel<32, 1><<<ab, 256, 0, stream>>>(g2, dinv, row_off, col,
                                              b2, pre2, nullptr, nullptr, x2, N);
    // --- layer 3 + output head
    gemm_mfma2<<<(N + 255) / 256, 256, 0, stream>>>(
        x2, Wt2, dinv, (__hip_bfloat16*)g3, N);
    agg_kernel<16, 2><<<ab, 256, 0, stream>>>(g3, dinv, row_off, col,
                                              b3, pre3, Wout, bout, d_out, N);
}